// Round 1
// baseline (655.840 us; speedup 1.0000x reference)
//
#include <hip/hip_runtime.h>
#include <math.h>

#define NODES_TOTAL 160000
#define NODES_REAL  5000
#define D 128
#define NEG 0.2f

// ---------------- CSR build (edge list is layer-invariant: build once/call) ----
__global__ void zero_counts(int* counts) {
    int i = blockIdx.x * blockDim.x + threadIdx.x;
    if (i < NODES_REAL) counts[i] = 0;
}

__global__ void hist_kernel(const int* __restrict__ ei, int* __restrict__ counts, int Eh) {
    int e = blockIdx.x * blockDim.x + threadIdx.x;
    if (e < Eh) atomicAdd(&counts[ei[Eh + e]], 1);
}

__global__ void scan_kernel(const int* __restrict__ counts, int* __restrict__ offs,
                            int* __restrict__ cursor) {
    __shared__ int sd[1024];
    int t = threadIdx.x;
    int pre[5]; int sum = 0;
    #pragma unroll
    for (int u = 0; u < 5; ++u) {
        int idx = t * 5 + u;
        int c = (idx < NODES_REAL) ? counts[idx] : 0;
        pre[u] = sum; sum += c;
    }
    sd[t] = sum;
    __syncthreads();
    int run = sum;
    for (int o = 1; o < 1024; o <<= 1) {
        int v = (t >= o) ? sd[t - o] : 0;
        __syncthreads();
        sd[t] += v;
        __syncthreads();
    }
    int excl = sd[t] - run;
    #pragma unroll
    for (int u = 0; u < 5; ++u) {
        int idx = t * 5 + u;
        if (idx < NODES_REAL) { int o = excl + pre[u]; offs[idx] = o; cursor[idx] = o; }
    }
    if (t == 1023) offs[NODES_REAL] = excl + run;
}

__global__ void scatter_kernel(const int* __restrict__ ei, int* __restrict__ cursor,
                               int* __restrict__ esrc, int Eh) {
    int e = blockIdx.x * blockDim.x + threadIdx.x;
    if (e < Eh) {
        int dv = ei[Eh + e];
        int pos = atomicAdd(&cursor[dv], 1);
        esrc[pos] = ei[e];
    }
}

// ---------------- GEMM: h2 = h @ W, fused epilogue -----------------------------
// rows >= 5000: only self-loop => out = relu(h2 + b) written directly.
// rows <  5000: write h2 to scratch (edge phase consumes it).
// W (64KB) in LDS once per block; h staged transposed in K-halves. 73KB LDS -> 2 blk/CU.
__global__ __launch_bounds__(256, 2)
void gemm_kernel(const float* __restrict__ hin, const float* __restrict__ W,
                 const float* __restrict__ bias, float* __restrict__ out,
                 float* __restrict__ h2) {
    __shared__ float Wl[D * D];        // [j][k], 64KB
    __shared__ float hTs[64 * 36];     // hT[j][r], pad 36 keeps float4 align + banks spread
    int tid = threadIdx.x;
    int dimgrp = tid & 31;             // dims 4*dimgrp .. +3
    int rowgrp = tid >> 5;             // rows 4*rowgrp .. +3 (within 32-row tile)
    // stage W (coalesced float4)
    {
        const float4* Wg = (const float4*)W;
        float4* Wd = (float4*)Wl;
        #pragma unroll
        for (int k = 0; k < 16; ++k) Wd[k * 256 + tid] = Wg[k * 256 + tid];
    }
    float4 b4 = *(const float4*)&bias[4 * dimgrp];
    int row0 = blockIdx.x * 64;
    for (int t = 0; t < 2; ++t) {
        int rb = row0 + t * 32;
        float4 acc[4];
        #pragma unroll
        for (int rr = 0; rr < 4; ++rr) acc[rr] = make_float4(0.f, 0.f, 0.f, 0.f);
        for (int jc = 0; jc < 2; ++jc) {
            __syncthreads();
            {   // stage 32 rows x 64 cols, transposed
                int r  = tid >> 3;
                int c0 = (tid & 7) * 8;
                const float* gp = hin + (size_t)(rb + r) * D + jc * 64 + c0;
                float4 v0 = *(const float4*)gp;
                float4 v1 = *(const float4*)(gp + 4);
                hTs[(c0 + 0) * 36 + r] = v0.x; hTs[(c0 + 1) * 36 + r] = v0.y;
                hTs[(c0 + 2) * 36 + r] = v0.z; hTs[(c0 + 3) * 36 + r] = v0.w;
                hTs[(c0 + 4) * 36 + r] = v1.x; hTs[(c0 + 5) * 36 + r] = v1.y;
                hTs[(c0 + 6) * 36 + r] = v1.z; hTs[(c0 + 7) * 36 + r] = v1.w;
            }
            __syncthreads();
            const float* wbase = Wl + jc * 64 * D + 4 * dimgrp;
            #pragma unroll 8
            for (int j = 0; j < 64; ++j) {
                float4 w4 = *(const float4*)(wbase + (size_t)j * D);
                float4 h4 = *(const float4*)&hTs[j * 36 + 4 * rowgrp];
                float hr[4] = {h4.x, h4.y, h4.z, h4.w};
                #pragma unroll
                for (int rr = 0; rr < 4; ++rr) {
                    acc[rr].x += hr[rr] * w4.x;
                    acc[rr].y += hr[rr] * w4.y;
                    acc[rr].z += hr[rr] * w4.z;
                    acc[rr].w += hr[rr] * w4.w;
                }
            }
        }
        // epilogue (registers only)
        #pragma unroll
        for (int rr = 0; rr < 4; ++rr) {
            int grow = rb + 4 * rowgrp + rr;
            float4 a = acc[rr];
            if (grow >= NODES_REAL) {
                float4 o;
                o.x = fmaxf(a.x + b4.x, 0.f);
                o.y = fmaxf(a.y + b4.y, 0.f);
                o.z = fmaxf(a.z + b4.z, 0.f);
                o.w = fmaxf(a.w + b4.w, 0.f);
                *(float4*)&out[(size_t)grow * D + 4 * dimgrp] = o;
            } else {
                *(float4*)&h2[(size_t)grow * D + 4 * dimgrp] = a;
            }
        }
    }
}

// ---------------- per-node attention scores s = h2.a_s, d = h2.a_d -------------
__global__ void score_kernel(const float* __restrict__ h2, const float* __restrict__ a_s,
                             const float* __restrict__ a_d, float* __restrict__ sv,
                             float* __restrict__ dv) {
    int row = blockIdx.x;
    int t = threadIdx.x;  // 128
    float v = h2[(size_t)row * D + t];
    float ps = v * a_s[t];
    float pd = v * a_d[t];
    #pragma unroll
    for (int o = 32; o > 0; o >>= 1) { ps += __shfl_down(ps, o); pd += __shfl_down(pd, o); }
    __shared__ float sb[4];
    if (t == 0)  { sb[0] = ps; sb[1] = pd; }
    if (t == 64) { sb[2] = ps; sb[3] = pd; }
    __syncthreads();
    if (t == 0) { sv[row] = sb[0] + sb[2]; dv[row] = sb[1] + sb[3]; }
}

// ---------------- softmax-weighted aggregation, one block per dst < 5000 -------
__global__ __launch_bounds__(256)
void agg_kernel(const float* __restrict__ h2, const float* __restrict__ sv,
                const float* __restrict__ dv, const int* __restrict__ offs,
                const int* __restrict__ esrc, const float* __restrict__ bias,
                float* __restrict__ out) {
    int i = blockIdx.x;
    int tid = threadIdx.x;
    int g = tid >> 5, l = tid & 31;   // 8 groups x 32 lanes
    int start = offs[i], end = offs[i + 1];
    float d_i = dv[i];
    float s_i = sv[i];
    float vse = s_i + d_i;
    float eself = vse > 0.f ? vse : NEG * vse;
    // pass 1: max
    float lm = eself;
    for (int e = start + tid; e < end; e += 256) {
        float v = sv[esrc[e]] + d_i;
        v = v > 0.f ? v : NEG * v;
        lm = fmaxf(lm, v);
    }
    #pragma unroll
    for (int o = 32; o > 0; o >>= 1) lm = fmaxf(lm, __shfl_xor(lm, o));
    __shared__ float wm[4];
    if ((tid & 63) == 0) wm[tid >> 6] = lm;
    __syncthreads();
    float m = fmaxf(fmaxf(wm[0], wm[1]), fmaxf(wm[2], wm[3]));
    // pass 2: exp-sum + weighted accumulate (lane l owns dims 4l..4l+3)
    float4 acc = make_float4(0.f, 0.f, 0.f, 0.f);
    float exsum = 0.f;
    for (int e = start + g; e < end; e += 8) {
        int src = esrc[e];
        float v = sv[src] + d_i;
        v = v > 0.f ? v : NEG * v;
        float ex = __expf(v - m);
        float4 hv = *(const float4*)&h2[(size_t)src * D + 4 * l];
        acc.x += ex * hv.x; acc.y += ex * hv.y; acc.z += ex * hv.z; acc.w += ex * hv.w;
        if (l == 0) exsum += ex;
    }
    if (g == 0) {  // self loop
        float ex = __expf(eself - m);
        float4 hv = *(const float4*)&h2[(size_t)i * D + 4 * l];
        acc.x += ex * hv.x; acc.y += ex * hv.y; acc.z += ex * hv.z; acc.w += ex * hv.w;
        if (l == 0) exsum += ex;
    }
    __shared__ float accs[8][128];
    __shared__ float exs[8];
    *(float4*)&accs[g][4 * l] = acc;
    if (l == 0) exs[g] = exsum;
    __syncthreads();
    if (tid < 128) {
        float tot = 0.f, den = 0.f;
        #pragma unroll
        for (int gg = 0; gg < 8; ++gg) { tot += accs[gg][tid]; den += exs[gg]; }
        float o = tot / den + bias[tid];
        out[(size_t)i * D + tid] = fmaxf(o, 0.f);
    }
}

// ---------------- launcher -----------------------------------------------------
extern "C" void kernel_launch(void* const* d_in, const int* in_sizes, int n_in,
                              void* d_out, int out_size, void* d_ws, size_t ws_size,
                              hipStream_t stream) {
    const float* x   = (const float*)d_in[0];
    const int*   ei  = (const int*)d_in[1];     // int per harness convention; values < 5000
    const float* Ws  = (const float*)d_in[2];
    const float* as_ = (const float*)d_in[3];
    const float* ad_ = (const float*)d_in[4];
    const float* bs  = (const float*)d_in[5];
    float* out = (float*)d_out;
    int Eh = in_sizes[1] / 2;                    // 1,280,000

    char* ws = (char*)d_ws;
    float* bufA  = (float*)ws;                         // 81,920,000 B
    float* h2    = (float*)(ws + 81920000);            //  2,560,000 B
    float* sv    = (float*)(ws + 84480000);            //     20,480 B
    float* dv    = (float*)(ws + 84500480);            //     20,480 B
    int*   counts= (int*)  (ws + 84520960);            //     20,480 B
    int*   offs  = (int*)  (ws + 84541440);            //     20,736 B (5001 ints)
    int*   cursor= (int*)  (ws + 84562176);            //     20,480 B
    int*   esrc  = (int*)  (ws + 84582656);            //  5,120,000 B  -> total ~89.7 MB

    // build CSR once per call (edge list identical across layers)
    zero_counts<<<(NODES_REAL + 255) / 256, 256, 0, stream>>>(counts);
    hist_kernel<<<(Eh + 255) / 256, 256, 0, stream>>>(ei, counts, Eh);
    scan_kernel<<<1, 1024, 0, stream>>>(counts, offs, cursor);
    scatter_kernel<<<(Eh + 255) / 256, 256, 0, stream>>>(ei, cursor, esrc, Eh);

    for (int l = 0; l < 3; ++l) {
        const float* hin = (l == 0) ? x : bufA;
        float* hout = (l == 2) ? out : bufA;   // in-place safe: per-row read-before-write
        gemm_kernel<<<NODES_TOTAL / 64, 256, 0, stream>>>(hin, Ws + l * D * D, bs + l * D,
                                                          hout, h2);
        score_kernel<<<NODES_REAL, 128, 0, stream>>>(h2, as_ + l * D, ad_ + l * D, sv, dv);
        agg_kernel<<<NODES_REAL, 256, 0, stream>>>(h2, sv, dv, offs, esrc, bs + l * D, hout);
    }
}

// Round 2
// 567.466 us; speedup vs baseline: 1.1557x; 1.1557x over previous
//
#include <hip/hip_runtime.h>
#include <math.h>

#define NODES_TOTAL 160000
#define NODES_REAL  5000
#define D 128
#define NEG 0.2f
#define KP 136                 // padded k-pitch in ushort units (128 + 8)
#define WT_L (2 * 128 * KP)    // per-layer ushorts (hi block + lo block) = 34816

typedef unsigned short ushort_t;
typedef __attribute__((ext_vector_type(8))) __bf16 bf16x8;
typedef __attribute__((ext_vector_type(4))) float f32x4;

union BF8 { bf16x8 v; ushort_t u[8]; };

__device__ __forceinline__ void split2(float x, ushort_t& hi, ushort_t& lo) {
    unsigned u = __float_as_uint(x);
    hi = (ushort_t)(u >> 16);
    float hif = __uint_as_float(u & 0xffff0000u);
    lo = (ushort_t)(__float_as_uint(x - hif) >> 16);
}

// ---------------- CSR build (edge list is layer-invariant: build once/call) ----
__global__ void zero_counts(int* counts) {
    int i = blockIdx.x * blockDim.x + threadIdx.x;
    if (i < NODES_REAL) counts[i] = 0;
}

__global__ void hist_kernel(const int* __restrict__ ei, int* __restrict__ counts, int Eh) {
    int e = blockIdx.x * blockDim.x + threadIdx.x;
    if (e < Eh) atomicAdd(&counts[ei[Eh + e]], 1);
}

__global__ void scan_kernel(const int* __restrict__ counts, int* __restrict__ offs,
                            int* __restrict__ cursor) {
    __shared__ int sd[1024];
    int t = threadIdx.x;
    int pre[5]; int sum = 0;
    #pragma unroll
    for (int u = 0; u < 5; ++u) {
        int idx = t * 5 + u;
        int c = (idx < NODES_REAL) ? counts[idx] : 0;
        pre[u] = sum; sum += c;
    }
    sd[t] = sum;
    __syncthreads();
    int run = sum;
    for (int o = 1; o < 1024; o <<= 1) {
        int v = (t >= o) ? sd[t - o] : 0;
        __syncthreads();
        sd[t] += v;
        __syncthreads();
    }
    int excl = sd[t] - run;
    #pragma unroll
    for (int u = 0; u < 5; ++u) {
        int idx = t * 5 + u;
        if (idx < NODES_REAL) { int o = excl + pre[u]; offs[idx] = o; cursor[idx] = o; }
    }
    if (t == 1023) offs[NODES_REAL] = excl + run;
}

__global__ void scatter_kernel(const int* __restrict__ ei, int* __restrict__ cursor,
                               int* __restrict__ esrc, int Eh) {
    int e = blockIdx.x * blockDim.x + threadIdx.x;
    if (e < Eh) {
        int dv = ei[Eh + e];
        int pos = atomicAdd(&cursor[dv], 1);
        esrc[pos] = ei[e];
    }
}

// ---------------- W split+transpose: Wt[l] = [hi: [n][KP]] [lo: [n][KP]] bf16 ----
// grid 24 (= 3 layers x 8), block 256. Thread: one (n, k0) chunk of 8 k's.
__global__ void wsplit_kernel(const float* __restrict__ Ws, ushort_t* __restrict__ Wt) {
    int l  = blockIdx.x >> 3;
    int n  = (blockIdx.x & 7) * 16 + (threadIdx.x >> 4);
    int k0 = (threadIdx.x & 15) * 8;
    const float* src = Ws + (size_t)l * D * D;
    union { ushort_t u[8]; uint4 v; } hi, lo;
    #pragma unroll
    for (int j = 0; j < 8; ++j) split2(src[(size_t)(k0 + j) * D + n], hi.u[j], lo.u[j]);
    ushort_t* dhi = Wt + (size_t)l * WT_L + n * KP + k0;
    *(uint4*)dhi = hi.v;
    *(uint4*)(dhi + 128 * KP) = lo.v;
}

// ---------------- GEMM: h2 = h @ W via split-bf16 MFMA, fused epilogue ---------
// Block tile 128 rows x 128 cols; 4 waves, wave = 2 row-tiles x 8 col-tiles (16x16x32).
// W (split bf16, padded [n][k]) staged linearly into LDS (69.6 KB -> 2 blocks/CU).
// A fragments read straight from global fp32 (32 B/lane contiguous) and split in reg.
__global__ __launch_bounds__(256, 2)
void gemm_mfma(const float* __restrict__ hin, const ushort_t* __restrict__ Wt,
               const float* __restrict__ bias, float* __restrict__ out,
               float* __restrict__ h2) {
    __shared__ ushort_t Wl[WT_L];   // hi[128][KP] then lo[128][KP]
    int tid = threadIdx.x;
    {   // stage 69632 B: 17 x (256 threads x 16 B), coalesced
        const uint4* gw = (const uint4*)Wt;
        uint4* lw = (uint4*)Wl;
        #pragma unroll
        for (int r = 0; r < 17; ++r) lw[r * 256 + tid] = gw[r * 256 + tid];
    }
    __syncthreads();

    int w    = tid >> 6;
    int lane = tid & 63;
    int q    = lane >> 4;       // quad: A/B frag k-offset q*8; C/D row base q*4
    int m16  = lane & 15;
    int row0 = blockIdx.x * 128 + w * 32;

    f32x4 acc[2][8];
    #pragma unroll
    for (int rt = 0; rt < 2; ++rt)
        #pragma unroll
        for (int ct = 0; ct < 8; ++ct) acc[rt][ct] = (f32x4){0.f, 0.f, 0.f, 0.f};

    const ushort_t* Whi = Wl;
    const ushort_t* Wlo = Wl + 128 * KP;

    #pragma unroll
    for (int kc = 0; kc < 4; ++kc) {
        BF8 ahi[2], alo[2];
        #pragma unroll
        for (int rt = 0; rt < 2; ++rt) {
            const float* gp = hin + (size_t)(row0 + rt * 16 + m16) * D + kc * 32 + q * 8;
            float4 v0 = *(const float4*)gp;
            float4 v1 = *(const float4*)(gp + 4);
            float xv[8] = {v0.x, v0.y, v0.z, v0.w, v1.x, v1.y, v1.z, v1.w};
            #pragma unroll
            for (int j = 0; j < 8; ++j) split2(xv[j], ahi[rt].u[j], alo[rt].u[j]);
        }
        #pragma unroll
        for (int ct = 0; ct < 8; ++ct) {
            int off = (ct * 16 + m16) * KP + kc * 32 + q * 8;
            bf16x8 bhi = *(const bf16x8*)&Whi[off];
            bf16x8 blo = *(const bf16x8*)&Wlo[off];
            #pragma unroll
            for (int rt = 0; rt < 2; ++rt) {
                acc[rt][ct] = __builtin_amdgcn_mfma_f32_16x16x32_bf16(ahi[rt].v, bhi, acc[rt][ct], 0, 0, 0);
                acc[rt][ct] = __builtin_amdgcn_mfma_f32_16x16x32_bf16(ahi[rt].v, blo, acc[rt][ct], 0, 0, 0);
                acc[rt][ct] = __builtin_amdgcn_mfma_f32_16x16x32_bf16(alo[rt].v, bhi, acc[rt][ct], 0, 0, 0);
            }
        }
    }

    // epilogue: C/D layout col = ct*16 + (lane&15), row = q*4 + reg (+ tile bases)
    float bv[8];
    #pragma unroll
    for (int ct = 0; ct < 8; ++ct) bv[ct] = bias[ct * 16 + m16];
    #pragma unroll
    for (int rt = 0; rt < 2; ++rt) {
        int rbase = row0 + rt * 16 + q * 4;
        #pragma unroll
        for (int reg = 0; reg < 4; ++reg) {
            int grow = rbase + reg;
            if (grow >= NODES_REAL) {
                #pragma unroll
                for (int ct = 0; ct < 8; ++ct)
                    out[(size_t)grow * D + ct * 16 + m16] = fmaxf(acc[rt][ct][reg] + bv[ct], 0.f);
            } else {
                #pragma unroll
                for (int ct = 0; ct < 8; ++ct)
                    h2[(size_t)grow * D + ct * 16 + m16] = acc[rt][ct][reg];
            }
        }
    }
}

// ---------------- per-node attention scores s = h2.a_s, d = h2.a_d -------------
__global__ void score_kernel(const float* __restrict__ h2, const float* __restrict__ a_s,
                             const float* __restrict__ a_d, float* __restrict__ sv,
                             float* __restrict__ dv) {
    int row = blockIdx.x;
    int t = threadIdx.x;  // 128
    float v = h2[(size_t)row * D + t];
    float ps = v * a_s[t];
    float pd = v * a_d[t];
    #pragma unroll
    for (int o = 32; o > 0; o >>= 1) { ps += __shfl_down(ps, o); pd += __shfl_down(pd, o); }
    __shared__ float sb[4];
    if (t == 0)  { sb[0] = ps; sb[1] = pd; }
    if (t == 64) { sb[2] = ps; sb[3] = pd; }
    __syncthreads();
    if (t == 0) { sv[row] = sb[0] + sb[2]; dv[row] = sb[1] + sb[3]; }
}

// ---------------- aggregation: one 64-lane wave per dst, online softmax --------
// lane owns dims {2*lane, 2*lane+1}. Edge indices loaded coalesced 64/chunk;
// per-chunk max + exp computed per-lane once, broadcast via shfl in gather loop.
__global__ __launch_bounds__(256)
void agg_kernel(const float* __restrict__ h2, const float* __restrict__ sv,
                const float* __restrict__ dv, const int* __restrict__ offs,
                const int* __restrict__ esrc, const float* __restrict__ bias,
                float* __restrict__ out) {
    int w = threadIdx.x >> 6, lane = threadIdx.x & 63;
    int i = blockIdx.x * 4 + w;               // grid 1250 -> i in [0,5000)
    int start = offs[i], end = offs[i + 1];
    float d_i = dv[i];
    float m = -1e30f, den = 0.f;
    float ax = 0.f, ay = 0.f;

    for (int base = start; base < end; base += 64) {
        int cnt = min(64, end - base);
        int srci = (lane < cnt) ? esrc[base + lane] : 0;
        float sc = (lane < cnt) ? sv[srci] + d_i : -1e30f;
        sc = sc > 0.f ? sc : NEG * sc;
        float cm = sc;
        #pragma unroll
        for (int o = 1; o < 64; o <<= 1) cm = fmaxf(cm, __shfl_xor(cm, o));
        float mn = fmaxf(m, cm);
        float scale = __expf(m - mn);
        float ex = __expf(sc - mn);           // invalid lanes -> 0
        float es = ex;
        #pragma unroll
        for (int o = 1; o < 64; o <<= 1) es += __shfl_xor(es, o);
        ax *= scale; ay *= scale;
        den = den * scale + es;
        m = mn;
        for (int j = 0; j < cnt; ++j) {
            int   src = __shfl(srci, j);
            float e   = __shfl(ex, j);
            float2 hv = *(const float2*)&h2[(size_t)src * D + 2 * lane];
            ax += e * hv.x; ay += e * hv.y;
        }
    }
    {   // self loop
        float sc = sv[i] + d_i; sc = sc > 0.f ? sc : NEG * sc;
        float mn = fmaxf(m, sc);
        float scale = __expf(m - mn);
        float ex = __expf(sc - mn);
        float2 hv = *(const float2*)&h2[(size_t)i * D + 2 * lane];
        ax = ax * scale + ex * hv.x;
        ay = ay * scale + ex * hv.y;
        den = den * scale + ex;
    }
    float2 b2 = *(const float2*)&bias[2 * lane];
    float rd = 1.f / den;
    float2 o2 = make_float2(fmaxf(ax * rd + b2.x, 0.f), fmaxf(ay * rd + b2.y, 0.f));
    *(float2*)&out[(size_t)i * D + 2 * lane] = o2;
}

// ---------------- launcher -----------------------------------------------------
extern "C" void kernel_launch(void* const* d_in, const int* in_sizes, int n_in,
                              void* d_out, int out_size, void* d_ws, size_t ws_size,
                              hipStream_t stream) {
    const float* x   = (const float*)d_in[0];
    const int*   ei  = (const int*)d_in[1];
    const float* Ws  = (const float*)d_in[2];
    const float* as_ = (const float*)d_in[3];
    const float* ad_ = (const float*)d_in[4];
    const float* bs  = (const float*)d_in[5];
    float* out = (float*)d_out;
    int Eh = in_sizes[1] / 2;                    // 1,280,000

    char* ws = (char*)d_ws;
    float*    bufA  = (float*)ws;                       // 81,920,000 B
    float*    h2    = (float*)(ws + 81920000);          //  2,560,000 B
    float*    sv    = (float*)(ws + 84480000);
    float*    dv    = (float*)(ws + 84500480);
    int*      counts= (int*)  (ws + 84520960);
    int*      offs  = (int*)  (ws + 84541440);
    int*      cursor= (int*)  (ws + 84562176);
    int*      esrc  = (int*)  (ws + 84582656);          //  5,120,000 B
    ushort_t* Wt    = (ushort_t*)(ws + 89702656);       //    208,896 B -> ~89.9 MB

    // one-time per call: CSR build + W split/transpose (inputs layer-invariant)
    zero_counts<<<(NODES_REAL + 255) / 256, 256, 0, stream>>>(counts);
    hist_kernel<<<(Eh + 255) / 256, 256, 0, stream>>>(ei, counts, Eh);
    scan_kernel<<<1, 1024, 0, stream>>>(counts, offs, cursor);
    scatter_kernel<<<(Eh + 255) / 256, 256, 0, stream>>>(ei, cursor, esrc, Eh);
    wsplit_kernel<<<24, 256, 0, stream>>>(Ws, Wt);

    for (int l = 0; l < 3; ++l) {
        const float* hin = (l == 0) ? x : bufA;
        float* hout = (l == 2) ? out : bufA;
        gemm_mfma<<<NODES_TOTAL / 128, 256, 0, stream>>>(hin, Wt + (size_t)l * WT_L,
                                                         bs + l * D, hout, h2);
        score_kernel<<<NODES_REAL, 128, 0, stream>>>(h2, as_ + l * D, ad_ + l * D, sv, dv);
        agg_kernel<<<NODES_REAL / 4, 256, 0, stream>>>(h2, sv, dv, offs, esrc, bs + l * D, hout);
    }
}